// Round 13
// baseline (829.756 us; speedup 1.0000x reference)
//
#include <hip/hip_runtime.h>
#include <cstdint>
#include <cstddef>

#define NB 32
#define NP 128
#define NR 16
#define ND 1024
#define RHOC 0.97f
#define EPSN 1e-8f
#define NBLK 768u

typedef short bf16x8 __attribute__((ext_vector_type(8)));
typedef float f32x4 __attribute__((ext_vector_type(4)));
typedef unsigned short u16x8 __attribute__((ext_vector_type(8)));
typedef unsigned short ushort_t;

__device__ inline ushort_t f2bf(float f) {
  unsigned u = __float_as_uint(f);
  unsigned r = (u + 0x7fffu + ((u >> 16) & 1u)) >> 16;
  return (ushort_t)r;
}
__device__ inline float bf2f(ushort_t v) {
  return __uint_as_float(((unsigned)v) << 16);
}
__device__ inline void gload16(const void* g, void* l) {
  __builtin_amdgcn_global_load_lds(
      (const __attribute__((address_space(1))) void*)g,
      (__attribute__((address_space(3))) void*)l, 16, 0, 0);
}

// ---- device-scope grid barrier (all NBLK blocks co-resident by construction)
__device__ inline void gridbar(unsigned* bar, unsigned tgt) {
  __threadfence();
  __syncthreads();
  if (threadIdx.x == 0) {
    __hip_atomic_fetch_add(bar, 1u, __ATOMIC_ACQ_REL, __HIP_MEMORY_SCOPE_AGENT);
    while (__hip_atomic_load(bar, __ATOMIC_ACQUIRE, __HIP_MEMORY_SCOPE_AGENT) < tgt)
      __builtin_amdgcn_s_sleep(8);
  }
  __syncthreads();
  __threadfence();
}

// ===================== phase-unit device functions (round-7 bodies) ==========

// convx: one wave converts one x-row to bf16 and writes its norm. No smem.
__device__ inline void convx_rowwave(int lane, int row, const float* __restrict__ x,
                                     ushort_t* __restrict__ Xb,
                                     float* __restrict__ xnorm) {
  const float* xr = x + (size_t)row * ND;
  ushort_t* xo = Xb + (size_t)row * ND;
  float ss = 0.f;
#pragma unroll
  for (int i = 0; i < 4; ++i) {
    float4 v = *(const float4*)&xr[i * 256 + lane * 4];
    ushort4 o;
    o.x = f2bf(v.x); o.y = f2bf(v.y); o.z = f2bf(v.z); o.w = f2bf(v.w);
    *(ushort4*)&xo[i * 256 + lane * 4] = o;
    ss += v.x * v.x + v.y * v.y + v.z * v.z + v.w * v.w;
  }
#pragma unroll
  for (int off = 32; off > 0; off >>= 1) ss += __shfl_xor(ss, off);
  if (lane == 0) xnorm[row] = sqrtf(ss);
}

__device__ inline void scalars_unit(int t, int b, const float* __restrict__ surprise,
                                    const void* __restrict__ mask,
                                    float* __restrict__ c, float* __restrict__ Abuf,
                                    float* __restrict__ csum, char* smem) {
  float* a_sh = (float*)smem;        // 128
  float* suf  = a_sh + 128;          // 129(+pad)
  float* redc = suf + 132;           // 128
  int*   isu8 = (int*)(redc + 128);
  const unsigned char* mb = (const unsigned char*)mask;
  if (t == 0) *isu8 = 0;
  __syncthreads();
  int v = 0;
  for (int i = t; i < NB * NP; i += 256)
    if ((i & 3) != 0 && mb[i] != 0) v = 1;
  if (v) *isu8 = 1;   // benign race: all writers write 1
  __syncthreads();
  int u8 = *isu8;
  if (t < NP) {
    int mv = u8 ? mb[b * NP + t] : ((const int*)mask)[b * NP + t];
    a_sh[t] = RHOC * (mv ? 0.f : 1.f);
  }
  __syncthreads();
  if (t == 0) {
    float p = 1.f;
    suf[NP] = 1.f;
    for (int s = NP - 1; s >= 0; --s) { p *= a_sh[s]; suf[s] = p; }
  }
  __syncthreads();
  if (t < NP) {
    float g = fminf(fmaxf(surprise[b * NP + t] * 0.2f, 0.f), 1.f);
    float cv = g * suf[t + 1];
    c[b * NP + t] = cv;
    redc[t] = cv;
  }
  __syncthreads();
  for (int off = 64; off > 0; off >>= 1) {
    if (t < off) redc[t] += redc[t + off];
    __syncthreads();
  }
  if (t == 0) { csum[b] = redc[0]; Abuf[b] = suf[0]; }
}

__device__ inline void convwt_unit(int t, int u, const float* __restrict__ Wk,
                                   ushort_t* __restrict__ WkT, char* smem) {
  ushort_t (*tt)[65] = (ushort_t(*)[65])smem;
  int k0 = (u >> 4) * 64, n0 = (u & 15) * 64;
#pragma unroll
  for (int i = 0; i < 16; ++i) {
    int r = i * 4 + (t >> 6), cc = t & 63;
    tt[r][cc] = f2bf(Wk[(size_t)(k0 + r) * ND + n0 + cc]);
  }
  __syncthreads();
#pragma unroll
  for (int i = 0; i < 16; ++i) {
    int r = i * 4 + (t >> 6), cc = t & 63;
    WkT[(size_t)(n0 + r) * ND + k0 + cc] = tt[cc][r];
  }
}

__device__ inline void convpk_unit(int t, int u, const float* __restrict__ pmK,
                                   ushort_t* __restrict__ pmKb) {
  size_t base = (size_t)u * 2048 + t * 8;
  float4 a = *(const float4*)&pmK[base];
  float4 bq = *(const float4*)&pmK[base + 4];
  u16x8 o;
  o[0] = f2bf(a.x); o[1] = f2bf(a.y); o[2] = f2bf(a.z); o[3] = f2bf(a.w);
  o[4] = f2bf(bq.x); o[5] = f2bf(bq.y); o[6] = f2bf(bq.z); o[7] = f2bf(bq.w);
  *(u16x8*)&pmKb[base] = o;
}

// kgemm 128x64 tile, BK=64, 4 waves (2x2), wave 64x32; swizzled LDS.
__device__ inline void kgemm_unit(int tid, int u, const ushort_t* __restrict__ Xb,
                                  const ushort_t* __restrict__ WkT,
                                  const float* __restrict__ bk,
                                  float* __restrict__ norms2p, char* smem) {
  ushort_t* As = (ushort_t*)smem;         // 128*64
  ushort_t* Bs = As + 128 * 64;           // 64*64
  float* sred = (float*)(Bs + 64 * 64);   // [2][128]
  int lane = tid & 63, wid = tid >> 6;
  int wr = wid >> 1, wc = wid & 1;
  int bm = u & 31, bn = u >> 5;  // bm%8 == u%8 == XCD: A-panel L2 reuse
  int m0 = bm * 128, n0 = bn * 64;
  int lo = lane & 15, hi = lane >> 4;
  f32x4 acc[4][2] = {};
  for (int k0 = 0; k0 < ND; k0 += 64) {
#pragma unroll
    for (int i = 0; i < 4; ++i) {
      int sl = i * 256 + tid;
      int r = sl >> 3, s = sl & 7;
      int gk = k0 + ((s ^ (r & 7)) << 3);
      gload16(&Xb[(size_t)(m0 + r) * ND + gk], &As[sl << 3]);
    }
#pragma unroll
    for (int i = 0; i < 2; ++i) {
      int sl = i * 256 + tid;
      int r = sl >> 3, s = sl & 7;
      int gk = k0 + ((s ^ (r & 7)) << 3);
      gload16(&WkT[(size_t)(n0 + r) * ND + gk], &Bs[sl << 3]);
    }
    __syncthreads();
#pragma unroll
    for (int ksl = 0; ksl < 2; ++ksl) {
      bf16x8 af[4], bfr[2];
#pragma unroll
      for (int mi = 0; mi < 4; ++mi) {
        int r = wr * 64 + mi * 16 + lo;
        int s = (ksl * 4 + hi) ^ (r & 7);
        af[mi] = *(const bf16x8*)&As[(r << 6) + (s << 3)];
      }
#pragma unroll
      for (int ni = 0; ni < 2; ++ni) {
        int r = wc * 32 + ni * 16 + lo;
        int s = (ksl * 4 + hi) ^ (r & 7);
        bfr[ni] = *(const bf16x8*)&Bs[(r << 6) + (s << 3)];
      }
#pragma unroll
      for (int mi = 0; mi < 4; ++mi)
#pragma unroll
        for (int ni = 0; ni < 2; ++ni)
          acc[mi][ni] = __builtin_amdgcn_mfma_f32_16x16x32_bf16(
              af[mi], bfr[ni], acc[mi][ni], 0, 0, 0);
    }
    __syncthreads();
  }
  float bkv[2];
#pragma unroll
  for (int ni = 0; ni < 2; ++ni) bkv[ni] = bk[n0 + wc * 32 + ni * 16 + lo];
#pragma unroll
  for (int mi = 0; mi < 4; ++mi) {
#pragma unroll
    for (int j = 0; j < 4; ++j) {
      float ss = 0.f;
#pragma unroll
      for (int ni = 0; ni < 2; ++ni) {
        float vv = acc[mi][ni][j] + bkv[ni];
        ss += vv * vv;
      }
      ss += __shfl_xor(ss, 1);
      ss += __shfl_xor(ss, 2);
      ss += __shfl_xor(ss, 4);
      ss += __shfl_xor(ss, 8);
      if (lo == 0) sred[wc * 128 + wr * 64 + mi * 16 + hi * 4 + j] = ss;
    }
  }
  __syncthreads();
  if (tid < 128)
    norms2p[(size_t)bn * (NB * NP) + m0 + tid] = sred[tid] + sred[128 + tid];
}

__device__ inline void hbar_unit(int tid, int u, const float* __restrict__ h,
                                 const float* __restrict__ c,
                                 float* __restrict__ hbar, char* smem) {
  int b = u >> 4, dchunk = u & 15;
  float* cs = (float*)smem;     // 128
  float* red = cs + 128;        // [4][64]
  int dd = tid & 63, sl = tid >> 6;
  int d = dchunk * 64 + dd;
  if (tid < NP) cs[tid] = c[b * NP + tid];
  __syncthreads();
  const float* hb = h + ((size_t)b * NP + sl * 32) * ND + d;
  float acc = 0.f;
#pragma unroll
  for (int tt2 = 0; tt2 < 32; ++tt2) acc += cs[sl * 32 + tt2] * hb[(size_t)tt2 * ND];
  red[sl * 64 + dd] = acc;
  __syncthreads();
  if (sl == 0)
    hbar[(size_t)b * ND + d] = red[dd] + red[64 + dd] + red[128 + dd] + red[192 + dd];
}

__device__ inline void ypm_unit(int tid, int u, const ushort_t* __restrict__ Xb,
                                const ushort_t* __restrict__ pmKb,
                                const float* __restrict__ pmV,
                                const float* __restrict__ pma,
                                const float* __restrict__ xnorm,
                                float* __restrict__ y, char* smem) {
  int b = u >> 3, p0 = (u & 7) * 16;
  float* sredp = (float*)smem;        // [4][16][17]
  float* wls = sredp + 4 * 16 * 17;   // [16][16]
  int lane = tid & 63, wid = tid >> 6;
  int lo = lane & 15, hi = lane >> 4;
  float4 v[16];
#pragma unroll
  for (int r = 0; r < 16; ++r)
    v[r] = *(const float4*)&pmV[((size_t)(b * NR + r)) * ND + tid * 4];
  const ushort_t* xrow = &Xb[((size_t)(b * NP + p0 + lo)) * ND];
  const ushort_t* krow = &pmKb[((size_t)(b * NR + lo)) * ND];
  f32x4 sc = {};
#pragma unroll
  for (int ki = 0; ki < 8; ++ki) {
    int koff = (wid * 8 + ki) * 32 + hi * 8;
    bf16x8 af = *(const bf16x8*)&xrow[koff];
    bf16x8 bf = *(const bf16x8*)&krow[koff];
    sc = __builtin_amdgcn_mfma_f32_16x16x32_bf16(af, bf, sc, 0, 0, 0);
  }
#pragma unroll
  for (int j = 0; j < 4; ++j) sredp[(wid * 16 + hi * 4 + j) * 17 + lo] = sc[j];
  __syncthreads();
  {
    int p = tid >> 4, r = tid & 15;
    float s = sredp[(p)*17 + r] + sredp[(16 + p) * 17 + r] +
              sredp[(32 + p) * 17 + r] + sredp[(48 + p) * 17 + r];
    wls[p * 16 + r] = pma[b * NR + r] * s / fmaxf(xnorm[b * NP + p0 + p], EPSN);
  }
  __syncthreads();
#pragma unroll
  for (int p = 0; p < 16; ++p) {
    float4 a = {0.f, 0.f, 0.f, 0.f};
#pragma unroll
    for (int r = 0; r < 16; ++r) {
      float w = wls[p * 16 + r];
      a.x += w * v[r].x; a.y += w * v[r].y;
      a.z += w * v[r].z; a.w += w * v[r].w;
    }
    *(float4*)&y[((size_t)(b * NP + p0 + p)) * ND + tid * 4] = a;
  }
}

__device__ inline void xbarw_unit(int tid, int u, const ushort_t* __restrict__ Xb,
                                  const float* __restrict__ norms2p,
                                  const float* __restrict__ c,
                                  float* __restrict__ xbar,
                                  float* __restrict__ wsum, char* smem) {
  float* wsh = (float*)smem;      // 128
  float* red = wsh + NP;          // [4][64][2]
  int b = u >> 3;
  int dd = tid & 63, sl = tid >> 6;
  int d = (u & 7) * 128 + dd * 2;
  if (tid < NP) {
    float s = 0.f;
#pragma unroll
    for (int pc = 0; pc < 16; ++pc)
      s += norms2p[(size_t)pc * (NB * NP) + b * NP + tid];
    wsh[tid] = c[b * NP + tid] / fmaxf(sqrtf(s), EPSN);
  }
  __syncthreads();
  if ((u & 7) == 0 && tid == 0) {
    float s = 0.f;
    for (int t2 = 0; t2 < NP; ++t2) s += wsh[t2];
    wsum[b] = s;
  }
  const ushort_t* xb = Xb + ((size_t)b * NP + sl * 32) * ND + d;
  float ax = 0.f, ay = 0.f;
#pragma unroll
  for (int t2 = 0; t2 < 32; ++t2) {
    unsigned uu = *(const unsigned*)&xb[(size_t)t2 * ND];
    float w = wsh[sl * 32 + t2];
    ax += w * bf2f((ushort_t)(uu & 0xffffu));
    ay += w * bf2f((ushort_t)(uu >> 16));
  }
  red[(sl * 64 + dd) * 2 + 0] = ax;
  red[(sl * 64 + dd) * 2 + 1] = ay;
  __syncthreads();
  if (sl == 0) {
    float2 o;
    o.x = red[dd * 2] + red[(64 + dd) * 2] + red[(128 + dd) * 2] + red[(192 + dd) * 2];
    o.y = red[dd * 2 + 1] + red[(64 + dd) * 2 + 1] + red[(128 + dd) * 2 + 1] +
          red[(192 + dd) * 2 + 1];
    *(float2*)&xbar[(size_t)b * ND + d] = o;
  }
}

__device__ inline void vkbar_unit(int t, int u, int path,
                                  const float* __restrict__ src,
                                  const float* __restrict__ W,
                                  float* __restrict__ partials, char* smem) {
  float (*hst)[36] = (float(*)[36])smem;  // [128][36], 18 KB
  int esl = u >> 4, dchunk = u & 15;
  int e0 = esl * 128, d0 = dchunk * 64;
#pragma unroll
  for (int i = 0; i < 16; ++i) {
    int idx = i * 256 + t;
    int bb = idx >> 7, e = idx & 127;
    hst[e][bb] = src[(size_t)bb * ND + e0 + e];
  }
  __syncthreads();
  int bg = t >> 6, dd = t & 63, d = d0 + dd;
  float acc[8] = {};
  for (int e = 0; e < 128; ++e) {
    float w = W[(size_t)(e0 + e) * ND + d];
    float4 h0 = *(const float4*)&hst[e][bg * 8];
    float4 h1 = *(const float4*)&hst[e][bg * 8 + 4];
    acc[0] += h0.x * w; acc[1] += h0.y * w; acc[2] += h0.z * w; acc[3] += h0.w * w;
    acc[4] += h1.x * w; acc[5] += h1.y * w; acc[6] += h1.z * w; acc[7] += h1.w * w;
  }
#pragma unroll
  for (int i = 0; i < 8; ++i)
    partials[((size_t)(path * 8 + esl) * NB + bg * 8 + i) * ND + d] = acc[i];
}

__device__ inline void epi_unit(int t, int u, int path,
                                const float* __restrict__ partials,
                                const float* __restrict__ bias,
                                const float* __restrict__ coef,
                                const float* __restrict__ e0p,
                                const float* __restrict__ Abuf,
                                float* __restrict__ out) {
  int b = u >> 2, dc = u & 3;
  int d = dc * 256 + t;
  float s = 0.f;
#pragma unroll
  for (int sl = 0; sl < 8; ++sl)
    s += partials[((size_t)(path * 8 + sl) * NB + b) * ND + d];
  s += coef[b] * bias[d];
  float A = Abuf[b];
#pragma unroll
  for (int r = 0; r < NR; ++r) {
    size_t idx = ((size_t)(b * NR + r)) * ND + d;
    out[idx] = A * e0p[idx] + s;
  }
}

// ===================== the persistent mega-kernel ============================
__global__ __launch_bounds__(256, 3) void mega_kernel(
    const float* __restrict__ surprise, const void* __restrict__ mask,
    const float* __restrict__ x, const float* __restrict__ h,
    const float* __restrict__ pmK, const float* __restrict__ pmV,
    const float* __restrict__ pma, const float* __restrict__ eK0,
    const float* __restrict__ eV0, const float* __restrict__ Wk,
    const float* __restrict__ bk, const float* __restrict__ Wv,
    const float* __restrict__ bv,
    unsigned* __restrict__ bar, float* __restrict__ c,
    float* __restrict__ Abuf, float* __restrict__ csum,
    float* __restrict__ wsum, float* __restrict__ hbar,
    float* __restrict__ xbar, float* __restrict__ norms2p,
    float* __restrict__ xnorm, float* __restrict__ partials,
    ushort_t* __restrict__ WkT, ushort_t* __restrict__ pmKb,
    ushort_t* __restrict__ Xb,
    float* __restrict__ y, float* __restrict__ outK, float* __restrict__ outV) {
  __shared__ __align__(16) char smem[25600];
  int bid = blockIdx.x;
  int tid = threadIdx.x;
  int lane = tid & 63, wid = tid >> 6;

  // ---- P1: convx (wave-per-row) + scalars + convpk + convwt ----
  for (int g = bid; g < 1024; g += (int)NBLK)
    convx_rowwave(lane, g * 4 + wid, x, Xb, xnorm);
  if (bid < NB) {
    scalars_unit(tid, bid, surprise, mask, c, Abuf, csum, smem);
  } else if (bid >= 256 && bid < 512) {
    convpk_unit(tid, bid - 256, pmK, pmKb);
  } else if (bid >= 512) {
    convwt_unit(tid, bid - 512, Wk, WkT, smem);
  }
  gridbar(&bar[0], NBLK);

  // ---- P2: kgemm(512) ∥ {hbar x2 + ypm}(256) ----
  if (bid < 512) {
    kgemm_unit(tid, bid, Xb, WkT, bk, norms2p, smem);
  } else {
    int j = bid - 512;
    hbar_unit(tid, j, h, c, hbar, smem);
    __syncthreads();
    hbar_unit(tid, j + 256, h, c, hbar, smem);
    __syncthreads();
    ypm_unit(tid, j, Xb, pmKb, pmV, pma, xnorm, y, smem);
  }
  gridbar(&bar[1], NBLK);

  // ---- P3: xbarw(256) ∥ vkbar-V(128) ----
  if (bid < 256) {
    xbarw_unit(tid, bid, Xb, norms2p, c, xbar, wsum, smem);
  } else if (bid < 384) {
    vkbar_unit(tid, bid - 256, 0, hbar, Wv, partials, smem);
  }
  gridbar(&bar[2], NBLK);

  // ---- P4: vkbar-K(128) ∥ epi-V(128) ----
  if (bid < 128) {
    vkbar_unit(tid, bid, 1, xbar, Wk, partials, smem);
  } else if (bid < 256) {
    epi_unit(tid, bid - 128, 0, partials, bv, csum, eV0, Abuf, outV);
  }
  gridbar(&bar[3], NBLK);

  // ---- P5: epi-K(128) ----
  if (bid < 128) {
    epi_unit(tid, bid, 1, partials, bk, wsum, eK0, Abuf, outK);
  }
}

extern "C" void kernel_launch(void* const* d_in, const int* in_sizes, int n_in,
                              void* d_out, int out_size, void* d_ws, size_t ws_size,
                              hipStream_t stream) {
  (void)in_sizes; (void)n_in; (void)out_size; (void)ws_size;
  const float* x_all    = (const float*)d_in[0];
  const float* h_all    = (const float*)d_in[1];
  const float* surprise = (const float*)d_in[2];
  const void*  mask     = d_in[3];
  const float* pmK      = (const float*)d_in[4];
  const float* pmV      = (const float*)d_in[5];
  const float* pma      = (const float*)d_in[6];
  const float* eK0      = (const float*)d_in[7];
  const float* eV0      = (const float*)d_in[8];
  const float* Wk       = (const float*)d_in[9];
  const float* bk       = (const float*)d_in[10];
  const float* Wv       = (const float*)d_in[11];
  const float* bv       = (const float*)d_in[12];

  float* y    = (float*)d_out;
  float* outK = y + (size_t)NB * NP * ND;
  float* outV = outK + (size_t)NB * NR * ND;

  char* w = (char*)d_ws;
  unsigned* bar   = (unsigned*)w; w += 256;
  float* c        = (float*)w; w += NB * NP * 4;               // 16 KB
  float* Abuf     = (float*)w; w += 256;
  float* csum     = (float*)w; w += 256;
  float* wsum     = (float*)w; w += 256;
  float* hbar     = (float*)w; w += NB * ND * 4;               // 128 KB
  float* xbar     = (float*)w; w += NB * ND * 4;               // 128 KB
  float* norms2p  = (float*)w; w += (size_t)16 * NB * NP * 4;  // 256 KB
  float* xnorm    = (float*)w; w += NB * NP * 4;               // 16 KB
  float* partials = (float*)w; w += (size_t)16 * NB * ND * 4;  // 2 MB
  ushort_t* WkT   = (ushort_t*)w; w += (size_t)ND * ND * 2;    // 2 MB
  ushort_t* pmKb  = (ushort_t*)w; w += (size_t)NB * NR * ND * 2;  // 1 MB
  ushort_t* Xb    = (ushort_t*)w; w += (size_t)NB * NP * ND * 2;  // 8 MB

  hipMemsetAsync(bar, 0, 256, stream);
  mega_kernel<<<NBLK, 256, 0, stream>>>(
      surprise, mask, x_all, h_all, pmK, pmV, pma, eK0, eV0, Wk, bk, Wv, bv,
      bar, c, Abuf, csum, wsum, hbar, xbar, norms2p, xnorm, partials, WkT,
      pmKb, Xb, y, outK, outV);
}

// Round 14
// 62.164 us; speedup vs baseline: 13.3478x; 13.3478x over previous
//
#include <hip/hip_runtime.h>
#include <cstdint>
#include <cstddef>

#define NB 32
#define NP 128
#define NR 16
#define ND 1024
#define RHOC 0.97f
#define EPSN 1e-8f

typedef short bf16x8 __attribute__((ext_vector_type(8)));
typedef float f32x4 __attribute__((ext_vector_type(4)));
typedef unsigned short ushort_t;

__device__ inline ushort_t f2bf(float f) {
  unsigned u = __float_as_uint(f);
  unsigned r = (u + 0x7fffu + ((u >> 16) & 1u)) >> 16;
  return (ushort_t)r;
}
__device__ inline float bf2f(ushort_t v) {
  return __uint_as_float(((unsigned)v) << 16);
}
// fast packed f32->bf16 (RNE), 4 instrs per 8 values
__device__ inline bf16x8 cvt8(float4 a, float4 b) {
  union { bf16x8 v; unsigned u[4]; } o;
  asm("v_cvt_pk_bf16_f32 %0, %1, %2" : "=v"(o.u[0]) : "v"(a.x), "v"(a.y));
  asm("v_cvt_pk_bf16_f32 %0, %1, %2" : "=v"(o.u[1]) : "v"(a.z), "v"(a.w));
  asm("v_cvt_pk_bf16_f32 %0, %1, %2" : "=v"(o.u[2]) : "v"(b.x), "v"(b.y));
  asm("v_cvt_pk_bf16_f32 %0, %1, %2" : "=v"(o.u[3]) : "v"(b.z), "v"(b.w));
  return o.v;
}
__device__ inline void gload16(const void* g, void* l) {
  __builtin_amdgcn_global_load_lds(
      (const __attribute__((address_space(1))) void*)g,
      (__attribute__((address_space(3))) void*)l, 16, 0, 0);
}

// ===== D1: ypm(256, f32-direct) + scalars(32) + convx(4096) + convwt(256) ====
__global__ __launch_bounds__(256) void prep_kernel(
    const float* __restrict__ surprise, const void* __restrict__ mask,
    const float* __restrict__ x, const float* __restrict__ Wk,
    const float* __restrict__ pmK, const float* __restrict__ pmV,
    const float* __restrict__ pma,
    float* __restrict__ c, float* __restrict__ Abuf, float* __restrict__ csum,
    ushort_t* __restrict__ Xb, ushort_t* __restrict__ WkT,
    float* __restrict__ y) {
  __shared__ __align__(16) char smem[8448];
  int bid = blockIdx.x;
  int t = threadIdx.x;
  if (bid < 256) {
    // ---- ypm: QK^T MFMA from f32 via cvt_pk; inline row norms; PV VALU ----
    int b = bid >> 3, p0 = (bid & 7) * 16;
    float* sredp = (float*)smem;          // [4][16][17]
    float* wls = sredp + 4 * 16 * 17;     // [16][16]
    float* rowssq = wls + 256;            // [4][16]
    int lane = t & 63, wid = t >> 6;
    int lo = lane & 15, hi = lane >> 4;
    float4 v[16];
#pragma unroll
    for (int r = 0; r < 16; ++r)
      v[r] = *(const float4*)&pmV[((size_t)(b * NR + r)) * ND + t * 4];
    const float* xrow = &x[((size_t)(b * NP + p0 + lo)) * ND];
    const float* krow = &pmK[((size_t)(b * NR + lo)) * ND];
    f32x4 sc = {};
    float ssq = 0.f;
#pragma unroll
    for (int ki = 0; ki < 8; ++ki) {
      int koff = (wid * 8 + ki) * 32 + hi * 8;
      float4 xa = *(const float4*)&xrow[koff];
      float4 xc = *(const float4*)&xrow[koff + 4];
      ssq += xa.x * xa.x + xa.y * xa.y + xa.z * xa.z + xa.w * xa.w +
             xc.x * xc.x + xc.y * xc.y + xc.z * xc.z + xc.w * xc.w;
      float4 ka = *(const float4*)&krow[koff];
      float4 kc = *(const float4*)&krow[koff + 4];
      sc = __builtin_amdgcn_mfma_f32_16x16x32_bf16(cvt8(xa, xc), cvt8(ka, kc),
                                                   sc, 0, 0, 0);
    }
    ssq += __shfl_xor(ssq, 16);
    ssq += __shfl_xor(ssq, 32);
    if (hi == 0) rowssq[wid * 16 + lo] = ssq;
#pragma unroll
    for (int j = 0; j < 4; ++j) sredp[(wid * 16 + hi * 4 + j) * 17 + lo] = sc[j];
    __syncthreads();
    {
      int p = t >> 4, r = t & 15;
      float s = sredp[p * 17 + r] + sredp[(16 + p) * 17 + r] +
                sredp[(32 + p) * 17 + r] + sredp[(48 + p) * 17 + r];
      float nrm = sqrtf(rowssq[p] + rowssq[16 + p] + rowssq[32 + p] + rowssq[48 + p]);
      wls[p * 16 + r] = pma[b * NR + r] * s / fmaxf(nrm, EPSN);
    }
    __syncthreads();
#pragma unroll
    for (int p = 0; p < 16; ++p) {
      float4 a = {0.f, 0.f, 0.f, 0.f};
#pragma unroll
      for (int r = 0; r < 16; ++r) {
        float w = wls[p * 16 + r];
        a.x += w * v[r].x; a.y += w * v[r].y;
        a.z += w * v[r].z; a.w += w * v[r].w;
      }
      *(float4*)&y[((size_t)(b * NP + p0 + p)) * ND + t * 4] = a;
    }
  } else if (bid < 256 + NB) {
    // ---- scalars: c, A, csum (+mask dtype detect) ----
    int b = bid - 256;
    float* a_sh = (float*)smem;        // 128
    float* suf  = a_sh + 128;          // 129(+pad)
    float* redc = suf + 132;           // 128
    int*   isu8 = (int*)(redc + 128);
    if (t == 0) *isu8 = 0;
    __syncthreads();
    const unsigned char* mb = (const unsigned char*)mask;
    int v = 0;
    for (int i = t; i < NB * NP; i += 256)
      if ((i & 3) != 0 && mb[i] != 0) v = 1;
    if (v) *isu8 = 1;   // benign race: all writers write 1
    __syncthreads();
    int u8 = *isu8;
    if (t < NP) {
      int mv = u8 ? mb[b * NP + t] : ((const int*)mask)[b * NP + t];
      a_sh[t] = RHOC * (mv ? 0.f : 1.f);
    }
    __syncthreads();
    if (t == 0) {
      float p = 1.f;
      suf[NP] = 1.f;
      for (int s = NP - 1; s >= 0; --s) { p *= a_sh[s]; suf[s] = p; }
    }
    __syncthreads();
    if (t < NP) {
      float g = fminf(fmaxf(surprise[b * NP + t] * 0.2f, 0.f), 1.f);
      float cv = g * suf[t + 1];
      c[b * NP + t] = cv;
      redc[t] = cv;
    }
    __syncthreads();
    for (int off = 64; off > 0; off >>= 1) {
      if (t < off) redc[t] += redc[t + off];
      __syncthreads();
    }
    if (t == 0) { csum[b] = redc[0]; Abuf[b] = suf[0]; }
  } else if (bid < 256 + NB + NB * NP) {
    // ---- convx: one x-row -> bf16 (no norm needed anymore) ----
    int row = bid - (256 + NB);
    float4 vv = *(const float4*)&x[(size_t)row * ND + t * 4];
    union { unsigned u[2]; ushort4 s4; } o;
    asm("v_cvt_pk_bf16_f32 %0, %1, %2" : "=v"(o.u[0]) : "v"(vv.x), "v"(vv.y));
    asm("v_cvt_pk_bf16_f32 %0, %1, %2" : "=v"(o.u[1]) : "v"(vv.z), "v"(vv.w));
    *(ushort4*)&Xb[(size_t)row * ND + t * 4] = o.s4;
  } else {
    // ---- convwt: Wk -> bf16 transposed [N][K] ----
    int id2 = bid - (256 + NB + NB * NP);
    ushort_t (*tt)[65] = (ushort_t(*)[65])smem;
    int k0 = (id2 >> 4) * 64, n0 = (id2 & 15) * 64;
#pragma unroll
    for (int i = 0; i < 16; ++i) {
      int r = i * 4 + (t >> 6), cc = t & 63;
      tt[r][cc] = f2bf(Wk[(size_t)(k0 + r) * ND + n0 + cc]);
    }
    __syncthreads();
#pragma unroll
    for (int i = 0; i < 16; ++i) {
      int r = i * 4 + (t >> 6), cc = t & 63;
      WkT[(size_t)(n0 + r) * ND + k0 + cc] = tt[cc][r];
    }
  }
}

// ===== D2: main = kgemm_norms(512) ∥ hbar(512) => 1024 blocks = 4/CU ========
__global__ __launch_bounds__(256) void main_kernel(
    const ushort_t* __restrict__ Xb, const ushort_t* __restrict__ WkT,
    const float* __restrict__ bk, float* __restrict__ norms2p,
    const float* __restrict__ h, const float* __restrict__ c,
    float* __restrict__ hbar) {
  __shared__ __align__(16) char smem[25600];
  int bid = blockIdx.x;
  int tid = threadIdx.x;
  if (bid < 512) {
    // ---- kgemm_norms: tile 128x64, BK=64, single-buf, 4 waves (2x2) ----
    ushort_t* As = (ushort_t*)smem;         // 128*64
    ushort_t* Bs = As + 128 * 64;           // 64*64
    float* sred = (float*)(Bs + 64 * 64);   // [2][128]
    int lane = tid & 63, wid = tid >> 6;
    int wr = wid >> 1, wc = wid & 1;
    int bm = bid & 31, bn = bid >> 5;  // bm%8 == bid%8 == XCD: A-panel L2 reuse
    int m0 = bm * 128, n0 = bn * 64;
    int lo = lane & 15, hi = lane >> 4;
    f32x4 acc[4][2] = {};
    for (int k0 = 0; k0 < ND; k0 += 64) {
#pragma unroll
      for (int i = 0; i < 4; ++i) {
        int sl = i * 256 + tid;
        int r = sl >> 3, s = sl & 7;
        int gk = k0 + ((s ^ (r & 7)) << 3);
        gload16(&Xb[(size_t)(m0 + r) * ND + gk], &As[sl << 3]);
      }
#pragma unroll
      for (int i = 0; i < 2; ++i) {
        int sl = i * 256 + tid;
        int r = sl >> 3, s = sl & 7;
        int gk = k0 + ((s ^ (r & 7)) << 3);
        gload16(&WkT[(size_t)(n0 + r) * ND + gk], &Bs[sl << 3]);
      }
      __syncthreads();
#pragma unroll
      for (int ksl = 0; ksl < 2; ++ksl) {
        bf16x8 af[4], bfr[2];
#pragma unroll
        for (int mi = 0; mi < 4; ++mi) {
          int r = wr * 64 + mi * 16 + lo;
          int s = (ksl * 4 + hi) ^ (r & 7);
          af[mi] = *(const bf16x8*)&As[(r << 6) + (s << 3)];
        }
#pragma unroll
        for (int ni = 0; ni < 2; ++ni) {
          int r = wc * 32 + ni * 16 + lo;
          int s = (ksl * 4 + hi) ^ (r & 7);
          bfr[ni] = *(const bf16x8*)&Bs[(r << 6) + (s << 3)];
        }
#pragma unroll
        for (int mi = 0; mi < 4; ++mi)
#pragma unroll
          for (int ni = 0; ni < 2; ++ni)
            acc[mi][ni] = __builtin_amdgcn_mfma_f32_16x16x32_bf16(
                af[mi], bfr[ni], acc[mi][ni], 0, 0, 0);
      }
      __syncthreads();
    }
    float bkv[2];
#pragma unroll
    for (int ni = 0; ni < 2; ++ni) bkv[ni] = bk[n0 + wc * 32 + ni * 16 + lo];
#pragma unroll
    for (int mi = 0; mi < 4; ++mi) {
#pragma unroll
      for (int j = 0; j < 4; ++j) {
        float ss = 0.f;
#pragma unroll
        for (int ni = 0; ni < 2; ++ni) {
          float vv = acc[mi][ni][j] + bkv[ni];
          ss += vv * vv;
        }
        ss += __shfl_xor(ss, 1);
        ss += __shfl_xor(ss, 2);
        ss += __shfl_xor(ss, 4);
        ss += __shfl_xor(ss, 8);
        if (lo == 0) sred[wc * 128 + wr * 64 + mi * 16 + hi * 4 + j] = ss;
      }
    }
    __syncthreads();
    if (tid < 128)
      norms2p[(size_t)bn * (NB * NP) + m0 + tid] = sred[tid] + sred[128 + tid];
  } else {
    // ---- hbar ----
    int id = bid - 512;
    int b = id >> 4, dchunk = id & 15;
    float* cs = (float*)smem;     // 128
    float* red = cs + 128;        // [4][64]
    int dd = tid & 63, sl = tid >> 6;
    int d = dchunk * 64 + dd;
    if (tid < NP) cs[tid] = c[b * NP + tid];
    __syncthreads();
    const float* hb = h + ((size_t)b * NP + sl * 32) * ND + d;
    float acc = 0.f;
#pragma unroll
    for (int tt2 = 0; tt2 < 32; ++tt2) acc += cs[sl * 32 + tt2] * hb[(size_t)tt2 * ND];
    red[sl * 64 + dd] = acc;
    __syncthreads();
    if (sl == 0)
      hbar[(size_t)b * ND + d] = red[dd] + red[64 + dd] + red[128 + dd] + red[192 + dd];
  }
}

// ===== vkbar body: partial[path*8+esl][b][d] over a 128-e slice, W read once.
__device__ __forceinline__ void vkbar_body(
    int id2, int t, int path, const float* __restrict__ src,
    const float* __restrict__ W, float* __restrict__ partials, char* smemv) {
  float (*hst)[36] = (float(*)[36])smemv;  // [128][36], 18 KB
  int esl = id2 >> 4, dchunk = id2 & 15;
  int e0 = esl * 128, d0 = dchunk * 64;
#pragma unroll
  for (int i = 0; i < 16; ++i) {
    int idx = i * 256 + t;
    int bb = idx >> 7, e = idx & 127;
    hst[e][bb] = src[(size_t)bb * ND + e0 + e];
  }
  __syncthreads();
  int bg = t >> 6, dd = t & 63, d = d0 + dd;
  float acc[8] = {};
  for (int e = 0; e < 128; ++e) {
    float w = W[(size_t)(e0 + e) * ND + d];
    float4 h0 = *(const float4*)&hst[e][bg * 8];
    float4 h1 = *(const float4*)&hst[e][bg * 8 + 4];
    acc[0] += h0.x * w; acc[1] += h0.y * w; acc[2] += h0.z * w; acc[3] += h0.w * w;
    acc[4] += h1.x * w; acc[5] += h1.y * w; acc[6] += h1.z * w; acc[7] += h1.w * w;
  }
#pragma unroll
  for (int i = 0; i < 8; ++i)
    partials[((size_t)(path * 8 + esl) * NB + bg * 8 + i) * ND + d] = acc[i];
}

// ===== epi body: out[b,r,:] = A*e0 + (sum_8 partials + coef*bias), one path ==
__device__ __forceinline__ void epi_body(
    int id2, int t, int path, const float* __restrict__ partials,
    const float* __restrict__ bias, const float* __restrict__ coef,
    const float* __restrict__ e0p, const float* __restrict__ Abuf,
    float* __restrict__ out) {
  int b = id2 >> 2, dc = id2 & 3;
  int d = dc * 256 + t;
  float s = 0.f;
#pragma unroll
  for (int sl = 0; sl < 8; ++sl)
    s += partials[((size_t)(path * 8 + sl) * NB + b) * ND + d];
  s += coef[b] * bias[d];
  float A = Abuf[b];
#pragma unroll
  for (int r = 0; r < NR; ++r) {
    size_t idx = ((size_t)(b * NR + r)) * ND + d;
    out[idx] = A * e0p[idx] + s;
  }
}

// ===== D3: xbarw(256) ∥ vkbarV(128) => 384 blocks ============================
__global__ __launch_bounds__(256) void d3_kernel(
    const ushort_t* __restrict__ Xb, const float* __restrict__ norms2p,
    const float* __restrict__ c, float* __restrict__ xbar,
    float* __restrict__ wsum,
    const float* __restrict__ hbar, const float* __restrict__ Wv,
    float* __restrict__ partials) {
  __shared__ __align__(16) char smem[18432];
  int bid = blockIdx.x;
  int tid = threadIdx.x;
  if (bid < 256) {
    // ---- xbarw: wsh = c/norm; xbar = sum_t wsh*x; wsum ----
    float* wsh = (float*)smem;      // 128
    float* red = wsh + NP;          // [4][64][2]
    int b = bid >> 3;
    int dd = tid & 63, sl = tid >> 6;
    int d = (bid & 7) * 128 + dd * 2;
    if (tid < NP) {
      float s = 0.f;
#pragma unroll
      for (int pc = 0; pc < 16; ++pc)
        s += norms2p[(size_t)pc * (NB * NP) + b * NP + tid];
      wsh[tid] = c[b * NP + tid] / fmaxf(sqrtf(s), EPSN);
    }
    __syncthreads();
    if ((bid & 7) == 0 && tid == 0) {
      float s = 0.f;
      for (int t2 = 0; t2 < NP; ++t2) s += wsh[t2];
      wsum[b] = s;
    }
    const ushort_t* xb = Xb + ((size_t)b * NP + sl * 32) * ND + d;
    float ax = 0.f, ay = 0.f;
#pragma unroll
    for (int t2 = 0; t2 < 32; ++t2) {
      unsigned u = *(const unsigned*)&xb[(size_t)t2 * ND];
      float w = wsh[sl * 32 + t2];
      ax += w * bf2f((ushort_t)(u & 0xffffu));
      ay += w * bf2f((ushort_t)(u >> 16));
    }
    red[(sl * 64 + dd) * 2 + 0] = ax;
    red[(sl * 64 + dd) * 2 + 1] = ay;
    __syncthreads();
    if (sl == 0) {
      float2 o;
      o.x = red[dd * 2] + red[(64 + dd) * 2] + red[(128 + dd) * 2] + red[(192 + dd) * 2];
      o.y = red[dd * 2 + 1] + red[(64 + dd) * 2 + 1] + red[(128 + dd) * 2 + 1] +
            red[(192 + dd) * 2 + 1];
      *(float2*)&xbar[(size_t)b * ND + d] = o;
    }
  } else {
    vkbar_body(bid - 256, tid, 0, hbar, Wv, partials, smem);
  }
}

// ===== D4: vkbarK(128) ∥ epiV(128) => 256 blocks =============================
__global__ __launch_bounds__(256) void d4_kernel(
    const float* __restrict__ xbar, const float* __restrict__ Wk,
    float* __restrict__ partials,
    const float* __restrict__ bv, const float* __restrict__ csum,
    const float* __restrict__ eV0, const float* __restrict__ Abuf,
    float* __restrict__ outV) {
  __shared__ __align__(16) char smem[18432];
  int bid = blockIdx.x;
  int tid = threadIdx.x;
  if (bid < 128) {
    vkbar_body(bid, tid, 1, xbar, Wk, partials, smem);
  } else {
    epi_body(bid - 128, tid, 0, partials, bv, csum, eV0, Abuf, outV);
  }
}

// ===== D5: epiK(128) =========================================================
__global__ __launch_bounds__(256) void d5_kernel(
    const float* __restrict__ partials, const float* __restrict__ bk,
    const float* __restrict__ wsum, const float* __restrict__ eK0,
    const float* __restrict__ Abuf, float* __restrict__ outK) {
  epi_body(blockIdx.x, threadIdx.x, 1, partials, bk, wsum, eK0, Abuf, outK);
}

extern "C" void kernel_launch(void* const* d_in, const int* in_sizes, int n_in,
                              void* d_out, int out_size, void* d_ws, size_t ws_size,
                              hipStream_t stream) {
  (void)in_sizes; (void)n_in; (void)out_size; (void)ws_size;
  const float* x_all    = (const float*)d_in[0];
  const float* h_all    = (const float*)d_in[1];
  const float* surprise = (const float*)d_in[2];
  const void*  mask     = d_in[3];
  const float* pmK      = (const float*)d_in[4];
  const float* pmV      = (const float*)d_in[5];
  const float* pma      = (const float*)d_in[6];
  const float* eK0      = (const float*)d_in[7];
  const float* eV0      = (const float*)d_in[8];
  const float* Wk       = (const float*)d_in[9];
  const float* bk       = (const float*)d_in[10];
  const float* Wv       = (const float*)d_in[11];
  const float* bv       = (const float*)d_in[12];

  float* y    = (float*)d_out;
  float* outK = y + (size_t)NB * NP * ND;
  float* outV = outK + (size_t)NB * NR * ND;

  char* w = (char*)d_ws;
  float* c        = (float*)w; w += NB * NP * 4;               // 16 KB
  float* Abuf     = (float*)w; w += 256;
  float* csum     = (float*)w; w += 256;
  float* wsum     = (float*)w; w += 256;
  float* hbar     = (float*)w; w += NB * ND * 4;               // 128 KB
  float* xbar     = (float*)w; w += NB * ND * 4;               // 128 KB
  float* norms2p  = (float*)w; w += (size_t)16 * NB * NP * 4;  // 256 KB
  float* partials = (float*)w; w += (size_t)16 * NB * ND * 4;  // 2 MB
  ushort_t* WkT   = (ushort_t*)w; w += (size_t)ND * ND * 2;    // 2 MB
  ushort_t* Xb    = (ushort_t*)w; w += (size_t)NB * NP * ND * 2;  // 8 MB

  prep_kernel<<<256 + NB + NB * NP + 256, 256, 0, stream>>>(
      surprise, mask, x_all, Wk, pmK, pmV, pma, c, Abuf, csum, Xb, WkT, y);
  main_kernel<<<512 + 512, 256, 0, stream>>>(Xb, WkT, bk, norms2p, h_all, c, hbar);
  d3_kernel<<<256 + 128, 256, 0, stream>>>(Xb, norms2p, c, xbar, wsum, hbar,
                                           Wv, partials);
  d4_kernel<<<128 + 128, 256, 0, stream>>>(xbar, Wk, partials, bv, csum, eV0,
                                           Abuf, outV);
  d5_kernel<<<128, 256, 0, stream>>>(partials, bk, wsum, eK0, Abuf, outK);
}

// Round 15
// 57.325 us; speedup vs baseline: 14.4747x; 1.0844x over previous
//
#include <hip/hip_runtime.h>
#include <cstdint>
#include <cstddef>

#define NB 32
#define NP 128
#define NR 16
#define ND 1024
#define RHOC 0.97f
#define EPSN 1e-8f

typedef short bf16x8 __attribute__((ext_vector_type(8)));
typedef float f32x4 __attribute__((ext_vector_type(4)));
typedef unsigned short u16x8 __attribute__((ext_vector_type(8)));
typedef unsigned short ushort_t;

__device__ inline ushort_t f2bf(float f) {
  unsigned u = __float_as_uint(f);
  unsigned r = (u + 0x7fffu + ((u >> 16) & 1u)) >> 16;
  return (ushort_t)r;
}
__device__ inline float bf2f(ushort_t v) {
  return __uint_as_float(((unsigned)v) << 16);
}
__device__ inline void gload16(const void* g, void* l) {
  __builtin_amdgcn_global_load_lds(
      (const __attribute__((address_space(1))) void*)g,
      (__attribute__((address_space(3))) void*)l, 16, 0, 0);
}

// ============ D1: prep = scalars(32) + convx(4096) + convwt(256) + convpk(256)
__global__ __launch_bounds__(256) void prep_kernel(
    const float* __restrict__ surprise, const void* __restrict__ mask,
    const float* __restrict__ x, const float* __restrict__ Wk,
    const float* __restrict__ pmK,
    float* __restrict__ c, float* __restrict__ Abuf, float* __restrict__ csum,
    ushort_t* __restrict__ Xb, float* __restrict__ xnorm,
    ushort_t* __restrict__ WkT, ushort_t* __restrict__ pmKb) {
  __shared__ __align__(16) char smem[8448];
  int bid = blockIdx.x;
  int t = threadIdx.x;
  if (bid < NB) {
    // ---- scalars: c, A, csum (+mask dtype detect) ----
    float* a_sh = (float*)smem;        // 128
    float* suf  = a_sh + 128;          // 129
    float* redc = suf + 132;           // 128
    int*   isu8 = (int*)(redc + 128);
    int b = bid;
    if (t == 0) *isu8 = 0;
    __syncthreads();
    const unsigned char* mb = (const unsigned char*)mask;
    int v = 0;
    for (int i = t; i < NB * NP; i += 256)
      if ((i & 3) != 0 && mb[i] != 0) v = 1;
    if (v) *isu8 = 1;   // benign race: all writers write 1
    __syncthreads();
    int u8 = *isu8;
    if (t < NP) {
      int mv = u8 ? mb[b * NP + t] : ((const int*)mask)[b * NP + t];
      a_sh[t] = RHOC * (mv ? 0.f : 1.f);
    }
    __syncthreads();
    if (t == 0) {
      float p = 1.f;
      suf[NP] = 1.f;
      for (int s = NP - 1; s >= 0; --s) { p *= a_sh[s]; suf[s] = p; }
    }
    __syncthreads();
    if (t < NP) {
      float g = fminf(fmaxf(surprise[b * NP + t] * 0.2f, 0.f), 1.f);
      float cv = g * suf[t + 1];
      c[b * NP + t] = cv;
      redc[t] = cv;
    }
    __syncthreads();
    for (int off = 64; off > 0; off >>= 1) {
      if (t < off) redc[t] += redc[t + off];
      __syncthreads();
    }
    if (t == 0) { csum[b] = redc[0]; Abuf[b] = suf[0]; }
  } else if (bid < NB + NB * NP) {
    // ---- convx: one x-row -> bf16 + norm (cvt_pk fast path) ----
    int row = bid - NB;
    float* red = (float*)smem;
    float4 vv = *(const float4*)&x[(size_t)row * ND + t * 4];
    union { unsigned u[2]; ushort4 s4; } o;
    asm("v_cvt_pk_bf16_f32 %0, %1, %2" : "=v"(o.u[0]) : "v"(vv.x), "v"(vv.y));
    asm("v_cvt_pk_bf16_f32 %0, %1, %2" : "=v"(o.u[1]) : "v"(vv.z), "v"(vv.w));
    *(ushort4*)&Xb[(size_t)row * ND + t * 4] = o.s4;
    float ss = vv.x * vv.x + vv.y * vv.y + vv.z * vv.z + vv.w * vv.w;
#pragma unroll
    for (int off = 32; off > 0; off >>= 1) ss += __shfl_xor(ss, off);
    int wave = t >> 6, lane = t & 63;
    if (lane == 0) red[wave] = ss;
    __syncthreads();
    if (t == 0) xnorm[row] = sqrtf(red[0] + red[1] + red[2] + red[3]);
  } else if (bid < NB + NB * NP + 256) {
    // ---- convwt: Wk -> bf16 transposed [N][K] ----
    int id2 = bid - (NB + NB * NP);
    ushort_t (*tt)[65] = (ushort_t(*)[65])smem;
    int k0 = (id2 >> 4) * 64, n0 = (id2 & 15) * 64;
#pragma unroll
    for (int i = 0; i < 16; ++i) {
      int r = i * 4 + (t >> 6), cc = t & 63;
      tt[r][cc] = f2bf(Wk[(size_t)(k0 + r) * ND + n0 + cc]);
    }
    __syncthreads();
#pragma unroll
    for (int i = 0; i < 16; ++i) {
      int r = i * 4 + (t >> 6), cc = t & 63;
      WkT[(size_t)(n0 + r) * ND + k0 + cc] = tt[cc][r];
    }
  } else {
    // ---- convpk: pmK f32 -> bf16, 2048 elems/block (cvt_pk fast path) ----
    int id3 = bid - (NB + NB * NP + 256);
    size_t base = (size_t)id3 * 2048 + t * 8;
    float4 a = *(const float4*)&pmK[base];
    float4 bq = *(const float4*)&pmK[base + 4];
    union { unsigned u[4]; u16x8 v; } o;
    asm("v_cvt_pk_bf16_f32 %0, %1, %2" : "=v"(o.u[0]) : "v"(a.x), "v"(a.y));
    asm("v_cvt_pk_bf16_f32 %0, %1, %2" : "=v"(o.u[1]) : "v"(a.z), "v"(a.w));
    asm("v_cvt_pk_bf16_f32 %0, %1, %2" : "=v"(o.u[2]) : "v"(bq.x), "v"(bq.y));
    asm("v_cvt_pk_bf16_f32 %0, %1, %2" : "=v"(o.u[3]) : "v"(bq.z), "v"(bq.w));
    *(u16x8*)&pmKb[base] = o.v;
  }
}

// ===== D2: main = kgemm_norms(512) ∥ hbar(512) => 1024 blocks ===============
__global__ __launch_bounds__(256) void main_kernel(
    const ushort_t* __restrict__ Xb, const ushort_t* __restrict__ WkT,
    const float* __restrict__ bk, float* __restrict__ norms2p,
    const float* __restrict__ h, const float* __restrict__ c,
    float* __restrict__ hbar) {
  __shared__ __align__(16) char smem[25600];
  int bid = blockIdx.x;
  int tid = threadIdx.x;
  if (bid < 512) {
    // ---- kgemm_norms: tile 128x64, BK=64, single-buf, 4 waves (2x2) ----
    ushort_t* As = (ushort_t*)smem;         // 128*64
    ushort_t* Bs = As + 128 * 64;           // 64*64
    float* sred = (float*)(Bs + 64 * 64);   // [2][128]
    int lane = tid & 63, wid = tid >> 6;
    int wr = wid >> 1, wc = wid & 1;
    int bm = bid & 31, bn = bid >> 5;  // bm%8 == bid%8 == XCD: A-panel L2 reuse
    int m0 = bm * 128, n0 = bn * 64;
    int lo = lane & 15, hi = lane >> 4;
    f32x4 acc[4][2] = {};
    for (int k0 = 0; k0 < ND; k0 += 64) {
#pragma unroll
      for (int i = 0; i < 4; ++i) {
        int sl = i * 256 + tid;
        int r = sl >> 3, s = sl & 7;
        int gk = k0 + ((s ^ (r & 7)) << 3);
        gload16(&Xb[(size_t)(m0 + r) * ND + gk], &As[sl << 3]);
      }
#pragma unroll
      for (int i = 0; i < 2; ++i) {
        int sl = i * 256 + tid;
        int r = sl >> 3, s = sl & 7;
        int gk = k0 + ((s ^ (r & 7)) << 3);
        gload16(&WkT[(size_t)(n0 + r) * ND + gk], &Bs[sl << 3]);
      }
      __syncthreads();
#pragma unroll
      for (int ksl = 0; ksl < 2; ++ksl) {
        bf16x8 af[4], bfr[2];
#pragma unroll
        for (int mi = 0; mi < 4; ++mi) {
          int r = wr * 64 + mi * 16 + lo;
          int s = (ksl * 4 + hi) ^ (r & 7);
          af[mi] = *(const bf16x8*)&As[(r << 6) + (s << 3)];
        }
#pragma unroll
        for (int ni = 0; ni < 2; ++ni) {
          int r = wc * 32 + ni * 16 + lo;
          int s = (ksl * 4 + hi) ^ (r & 7);
          bfr[ni] = *(const bf16x8*)&Bs[(r << 6) + (s << 3)];
        }
#pragma unroll
        for (int mi = 0; mi < 4; ++mi)
#pragma unroll
          for (int ni = 0; ni < 2; ++ni)
            acc[mi][ni] = __builtin_amdgcn_mfma_f32_16x16x32_bf16(
                af[mi], bfr[ni], acc[mi][ni], 0, 0, 0);
      }
      __syncthreads();
    }
    float bkv[2];
#pragma unroll
    for (int ni = 0; ni < 2; ++ni) bkv[ni] = bk[n0 + wc * 32 + ni * 16 + lo];
#pragma unroll
    for (int mi = 0; mi < 4; ++mi) {
#pragma unroll
      for (int j = 0; j < 4; ++j) {
        float ss = 0.f;
#pragma unroll
        for (int ni = 0; ni < 2; ++ni) {
          float vv = acc[mi][ni][j] + bkv[ni];
          ss += vv * vv;
        }
        ss += __shfl_xor(ss, 1);
        ss += __shfl_xor(ss, 2);
        ss += __shfl_xor(ss, 4);
        ss += __shfl_xor(ss, 8);
        if (lo == 0) sred[wc * 128 + wr * 64 + mi * 16 + hi * 4 + j] = ss;
      }
    }
    __syncthreads();
    if (tid < 128)
      norms2p[(size_t)bn * (NB * NP) + m0 + tid] = sred[tid] + sred[128 + tid];
  } else {
    // ---- hbar ----
    int id = bid - 512;
    int b = id >> 4, dchunk = id & 15;
    float* cs = (float*)smem;     // 128
    float* red = cs + 128;        // [4][64]
    int dd = tid & 63, sl = tid >> 6;
    int d = dchunk * 64 + dd;
    if (tid < NP) cs[tid] = c[b * NP + tid];
    __syncthreads();
    const float* hb = h + ((size_t)b * NP + sl * 32) * ND + d;
    float acc = 0.f;
#pragma unroll
    for (int tt2 = 0; tt2 < 32; ++tt2) acc += cs[sl * 32 + tt2] * hb[(size_t)tt2 * ND];
    red[sl * 64 + dd] = acc;
    __syncthreads();
    if (sl == 0)
      hbar[(size_t)b * ND + d] = red[dd] + red[64 + dd] + red[128 + dd] + red[192 + dd];
  }
}

// ============ D3: mid = xbarw(256) ∥ ypm2(256) ==============================
__global__ __launch_bounds__(256) void mid_kernel(
    const ushort_t* __restrict__ Xb, const float* __restrict__ norms2p,
    const float* __restrict__ c, float* __restrict__ xbar,
    float* __restrict__ wsum, const ushort_t* __restrict__ pmKb,
    const float* __restrict__ pmV, const float* __restrict__ pma,
    const float* __restrict__ xnorm, float* __restrict__ y) {
  __shared__ __align__(16) char smem[5504];
  int bid = blockIdx.x;
  int tid = threadIdx.x;
  if (bid < 256) {
    // ---- xbarw: wsh = c/norm; xbar = sum_t wsh*x; wsum ----
    float* wsh = (float*)smem;      // 128
    float* red = wsh + NP;          // [4][64][2]
    int b = bid >> 3;
    int dd = tid & 63, sl = tid >> 6;
    int d = (bid & 7) * 128 + dd * 2;
    if (tid < NP) {
      float s = 0.f;
#pragma unroll
      for (int pc = 0; pc < 16; ++pc)
        s += norms2p[(size_t)pc * (NB * NP) + b * NP + tid];
      wsh[tid] = c[b * NP + tid] / fmaxf(sqrtf(s), EPSN);
    }
    __syncthreads();
    if ((bid & 7) == 0 && tid == 0) {
      float s = 0.f;
      for (int t2 = 0; t2 < NP; ++t2) s += wsh[t2];
      wsum[b] = s;
    }
    const ushort_t* xb = Xb + ((size_t)b * NP + sl * 32) * ND + d;
    float ax = 0.f, ay = 0.f;
#pragma unroll
    for (int t2 = 0; t2 < 32; ++t2) {
      unsigned u = *(const unsigned*)&xb[(size_t)t2 * ND];
      float w = wsh[sl * 32 + t2];
      ax += w * bf2f((ushort_t)(u & 0xffffu));
      ay += w * bf2f((ushort_t)(u >> 16));
    }
    red[(sl * 64 + dd) * 2 + 0] = ax;
    red[(sl * 64 + dd) * 2 + 1] = ay;
    __syncthreads();
    if (sl == 0) {
      float2 o;
      o.x = red[dd * 2] + red[(64 + dd) * 2] + red[(128 + dd) * 2] + red[(192 + dd) * 2];
      o.y = red[dd * 2 + 1] + red[(64 + dd) * 2 + 1] + red[(128 + dd) * 2 + 1] +
            red[(192 + dd) * 2 + 1];
      *(float2*)&xbar[(size_t)b * ND + d] = o;
    }
  } else {
    // ---- ypm2: QK^T MFMA direct-from-global; PV in VALU ----
    int id2 = bid - 256;
    int b = id2 >> 3, p0 = (id2 & 7) * 16;
    float* sredp = (float*)smem;        // [4][16][17]
    float* wls = sredp + 4 * 16 * 17;   // [16][16]
    int lane = tid & 63, wid = tid >> 6;
    int lo = lane & 15, hi = lane >> 4;
    // prefetch pmV
    float4 v[16];
#pragma unroll
    for (int r = 0; r < 16; ++r)
      v[r] = *(const float4*)&pmV[((size_t)(b * NR + r)) * ND + tid * 4];
    // QK^T: wave wid covers K range [wid*256, wid*256+256)
    const ushort_t* xrow = &Xb[((size_t)(b * NP + p0 + lo)) * ND];
    const ushort_t* krow = &pmKb[((size_t)(b * NR + lo)) * ND];
    f32x4 sc = {};
#pragma unroll
    for (int ki = 0; ki < 8; ++ki) {
      int koff = (wid * 8 + ki) * 32 + hi * 8;
      bf16x8 af = *(const bf16x8*)&xrow[koff];
      bf16x8 bf = *(const bf16x8*)&krow[koff];
      sc = __builtin_amdgcn_mfma_f32_16x16x32_bf16(af, bf, sc, 0, 0, 0);
    }
#pragma unroll
    for (int j = 0; j < 4; ++j) sredp[(wid * 16 + hi * 4 + j) * 17 + lo] = sc[j];
    __syncthreads();
    {
      int p = tid >> 4, r = tid & 15;
      float s = sredp[(p)*17 + r] + sredp[(16 + p) * 17 + r] +
                sredp[(32 + p) * 17 + r] + sredp[(48 + p) * 17 + r];
      wls[p * 16 + r] = pma[b * NR + r] * s / fmaxf(xnorm[b * NP + p0 + p], EPSN);
    }
    __syncthreads();
#pragma unroll
    for (int p = 0; p < 16; ++p) {
      float4 a = {0.f, 0.f, 0.f, 0.f};
#pragma unroll
      for (int r = 0; r < 16; ++r) {
        float w = wls[p * 16 + r];
        a.x += w * v[r].x; a.y += w * v[r].y;
        a.z += w * v[r].z; a.w += w * v[r].w;
      }
      *(float4*)&y[((size_t)(b * NP + p0 + p)) * ND + tid * 4] = a;
    }
  }
}

// ============ D4: vkbar: partial[path][esl][b][d] over 128-e slice ===========
// W read exactly once. 256 blocks: path(2) x esl(8) x dchunk(16); 256 thr.
__global__ __launch_bounds__(256) void vkbar_kernel(
    const float* __restrict__ hbar, const float* __restrict__ xbar,
    const float* __restrict__ Wv, const float* __restrict__ Wk,
    float* __restrict__ partials) {
  __shared__ __align__(16) float hst[128][36];  // transposed src slice, 18 KB
  int bid = blockIdx.x;
  int path = bid >> 7;
  int id2 = bid & 127;
  int esl = id2 >> 4, dchunk = id2 & 15;
  int e0 = esl * 128, d0 = dchunk * 64;
  const float* src = path ? xbar : hbar;
  const float* W = path ? Wk : Wv;
  int t = threadIdx.x;
#pragma unroll
  for (int i = 0; i < 16; ++i) {
    int idx = i * 256 + t;
    int bb = idx >> 7, e = idx & 127;
    hst[e][bb] = src[(size_t)bb * ND + e0 + e];
  }
  __syncthreads();
  int bg = t >> 6, dd = t & 63, d = d0 + dd;
  float acc[8] = {};
  for (int e = 0; e < 128; ++e) {
    float w = W[(size_t)(e0 + e) * ND + d];
    float4 h0 = *(const float4*)&hst[e][bg * 8];
    float4 h1 = *(const float4*)&hst[e][bg * 8 + 4];
    acc[0] += h0.x * w; acc[1] += h0.y * w; acc[2] += h0.z * w; acc[3] += h0.w * w;
    acc[4] += h1.x * w; acc[5] += h1.y * w; acc[6] += h1.z * w; acc[7] += h1.w * w;
  }
#pragma unroll
  for (int i = 0; i < 8; ++i)
    partials[((size_t)(path * 8 + esl) * NB + bg * 8 + i) * ND + d] = acc[i];
}

// ============ D5: epi: out = A*e0 + (sum partials + coef*bias) ===============
// 256 blocks: path(2) x b(32) x dchunk(4); 256 thr.
__global__ __launch_bounds__(256) void epi_kernel(
    const float* __restrict__ partials, const float* __restrict__ bv,
    const float* __restrict__ bk, const float* __restrict__ eV0,
    const float* __restrict__ eK0, const float* __restrict__ Abuf,
    const float* __restrict__ csum, const float* __restrict__ wsum,
    float* __restrict__ outV, float* __restrict__ outK) {
  int bid = blockIdx.x;
  int path = bid >> 7;
  int id2 = bid & 127;
  int b = id2 >> 2, dc = id2 & 3;
  int d = dc * 256 + threadIdx.x;
  float s = 0.f;
#pragma unroll
  for (int sl = 0; sl < 8; ++sl)
    s += partials[((size_t)(path * 8 + sl) * NB + b) * ND + d];
  const float* bias = path ? bk : bv;
  const float* coef = path ? wsum : csum;
  const float* e0p = path ? eK0 : eV0;
  float* out = path ? outK : outV;
  s += coef[b] * bias[d];
  float A = Abuf[b];
#pragma unroll
  for (int r = 0; r < NR; ++r) {
    size_t idx = ((size_t)(b * NR + r)) * ND + d;
    out[idx] = A * e0p[idx] + s;
  }
}

extern "C" void kernel_launch(void* const* d_in, const int* in_sizes, int n_in,
                              void* d_out, int out_size, void* d_ws, size_t ws_size,
                              hipStream_t stream) {
  (void)in_sizes; (void)n_in; (void)out_size; (void)ws_size;
  const float* x_all    = (const float*)d_in[0];
  const float* h_all    = (const float*)d_in[1];
  const float* surprise = (const float*)d_in[2];
  const void*  mask     = d_in[3];
  const float* pmK      = (const float*)d_in[4];
  const float* pmV      = (const float*)d_in[5];
  const float* pma      = (const float*)d_in[6];
  const float* eK0      = (const float*)d_in[7];
  const float* eV0      = (const float*)d_in[8];
  const float* Wk       = (const float*)d_in[9];
  const float* bk       = (const float*)d_in[10];
  const float* Wv       = (const float*)d_in[11];
  const float* bv       = (const float*)d_in[12];

  float* y    = (float*)d_out;
  float* outK = y + (size_t)NB * NP * ND;
  float* outV = outK + (size_t)NB * NR * ND;

  char* w = (char*)d_ws;
  float* c        = (float*)w; w += NB * NP * 4;               // 16 KB
  float* Abuf     = (float*)w; w += 256;
  float* csum     = (float*)w; w += 256;
  float* wsum     = (float*)w; w += 256;
  float* hbar     = (float*)w; w += NB * ND * 4;               // 128 KB
  float* xbar     = (float*)w; w += NB * ND * 4;               // 128 KB
  float* norms2p  = (float*)w; w += (size_t)16 * NB * NP * 4;  // 256 KB
  float* xnorm    = (float*)w; w += NB * NP * 4;               // 16 KB
  float* partials = (float*)w; w += (size_t)16 * NB * ND * 4;  // 2 MB
  ushort_t* WkT   = (ushort_t*)w; w += (size_t)ND * ND * 2;    // 2 MB
  ushort_t* pmKb  = (ushort_t*)w; w += (size_t)NB * NR * ND * 2;  // 1 MB
  ushort_t* Xb    = (ushort_t*)w; w += (size_t)NB * NP * ND * 2;  // 8 MB

  prep_kernel<<<NB + NB * NP + 256 + 256, 256, 0, stream>>>(
      surprise, mask, x_all, Wk, pmK, c, Abuf, csum, Xb, xnorm, WkT, pmKb);
  main_kernel<<<512 + 512, 256, 0, stream>>>(Xb, WkT, bk, norms2p, h_all, c, hbar);
  mid_kernel<<<256 + 256, 256, 0, stream>>>(Xb, norms2p, c, xbar, wsum, pmKb,
                                            pmV, pma, xnorm, y);
  vkbar_kernel<<<256, 256, 0, stream>>>(hbar, xbar, Wv, Wk, partials);
  epi_kernel<<<256, 256, 0, stream>>>(partials, bv, bk, eV0, eK0, Abuf, csum,
                                      wsum, outV, outK);
}